// Round 26
// baseline (123.678 us; speedup 1.0000x reference)
//
#include <hip/hip_runtime.h>

typedef __attribute__((ext_vector_type(4))) _Float16 f16x4;
typedef __attribute__((ext_vector_type(8))) _Float16 f16x8;
typedef __attribute__((ext_vector_type(4))) float f32x4;

#define NB 4096
#define TT 200
#define DD 64
#define H0 128
#define H1 64
#define BT 512   // 8 waves: waves 0-3 -> b0, waves 4-7 -> b1

// ws layout (bytes)
#define WS_BC 0        // W0bcT fp16 [128][64] = 16384 B  (W0b - W0c, transposed)
#define WS_DD 16384    // W0dT  fp16 [128][64] = 16384 B  (W0d, transposed)
#define WS_W1 32768    // W1phi fp16 [64][128] = 16384 B  (phi-permuted, XOR-swizzled)
#define WS_CB 49152    // cb f32 [4096][128] = 2 MB

// ---- pre-kernel A: fold W0 -> fp16 transposed parts + phi-permuted W1 image ----
// phi(g4,jj) = 4*g4 + (jj&3) + 16*(jj>>2): the k-labeling that matches the
// layer0 D-fragment layout, so layer1's A-frag is ONE b128 per (c1,m).
// W1 image XOR-swizzled on 16B units: unit ^= (row & 15) -> conflict-free b128.
__global__ __launch_bounds__(256)
void pre_fold(const float* __restrict__ W0, const float* __restrict__ W1,
              unsigned char* __restrict__ ws)
{
  int idx = blockIdx.x * 256 + threadIdx.x;   // grid 64 -> 16384 threads
  _Float16* bcT  = (_Float16*)(ws + WS_BC);
  _Float16* ddT  = (_Float16*)(ws + WS_DD);
  _Float16* w1p  = (_Float16*)(ws + WS_W1);
  if (idx < 8192) {
    int h = idx >> 6, d = idx & 63;
    bcT[h * 64 + d] = (_Float16)(W0[(64 + d) * H0 + h] - W0[(128 + d) * H0 + h]);
    ddT[h * 64 + d] = (_Float16)(W0[(192 + d) * H0 + h]);
  } else {
    int i = idx - 8192;                       // 0..8191
    int jrow = i >> 7, p = i & 127;           // p = m*32 + g4p*8 + jj
    int m = p >> 5, g4p = (p >> 3) & 3, jj = p & 7;
    int h = 32 * m + 16 * (jj >> 2) + 4 * g4p + (jj & 3);
    int up = p >> 3, wi = p & 7;              // 16B unit, half-within-unit
    w1p[jrow * 128 + (((up ^ (jrow & 15)) << 3) | wi)] = (_Float16)W1[h * H1 + jrow];
  }
}

// ---- pre-kernel B: cb[b][h] = b0[h] + q[b] @ (W0a + W0c) ----
__global__ __launch_bounds__(256)
void pre_cb(const float* __restrict__ q, const float* __restrict__ W0,
            const float* __restrict__ b0, unsigned char* __restrict__ ws)
{
  __shared__ float WacS[DD * H0];   // 32 KB, [d][h]
  __shared__ float qS2[2][DD];
  const int tid = threadIdx.x;
  float* cb = (float*)(ws + WS_CB);

  #pragma unroll 4
  for (int i = 0; i < 32; ++i) {
    int idx = i * 256 + tid;
    int d = idx >> 7, h = idx & 127;
    WacS[idx] = W0[d * H0 + h] + W0[(128 + d) * H0 + h];
  }
  __syncthreads();

  const int half = tid >> 7, h = tid & 127;
  #pragma unroll 1
  for (int p = 0; p < 16; ++p) {
    int bpair = blockIdx.x * 32 + p * 2;      // grid 128
    if (tid < DD) qS2[0][tid] = q[(size_t)bpair * DD + tid];
    else if (tid >= 128 && tid < 128 + DD) qS2[1][tid - 128] = q[(size_t)(bpair + 1) * DD + (tid - 128)];
    __syncthreads();
    float s = b0[h];
    #pragma unroll 8
    for (int d = 0; d < DD; ++d) s = fmaf(qS2[half][d], WacS[d * H0 + h], s);
    cb[(size_t)(bpair + half) * H0 + h] = s;
    __syncthreads();
  }
}

// ---- main kernel ----
// Transposed-GEMM DIN attention, fp16 weights/acts, fp32 accum/softmax, both
// layers on mfma_f32_16x16x32_f16 (k-relabeling: layer1 uses phi = D-frag
// layout; exact since k is contracted and A/B lane->k maps are identical).
// R26 = R21 restored EXACTLY (the verified 114 us optimum). R25's setprio
// regressed (123 us, 9 MB spill-writes: the priority toggles perturbed
// scheduling/regalloc; structure is quasi-lockstep, the T5-null regime).
// Design-space map (R0-R25): occupancy bounded at 16 waves/CU by the unique
// clean register point (512,4); tighter/looser bounds spill or balloon; ILP,
// prologue-amortization, persistence, prefetch, early-v, setprio all
// neutral-or-regress. Latency-structure plateau ~1.7x the 67 us HBM floor.
__global__ __launch_bounds__(BT, 4)
void din_attn(const float* __restrict__ q, const float* __restrict__ k,
              const float* __restrict__ v, const int* __restrict__ mask,
              const float* __restrict__ b1, const float* __restrict__ Wf,
              const unsigned char* __restrict__ ws, float* __restrict__ out)
{
  const int tid  = threadIdx.x;    // 0..511
  const int bloc = tid >> 8;       // 0/1: which b of the pair
  const int t256 = tid & 255;      // thread id within the b-group
  const int lane = tid & 63;
  const int wid4 = (tid >> 6) & 3; // wave within the b-group
  const int r16  = lane & 15;
  const int g4   = lane >> 4;
  const int b    = blockIdx.x * 2 + bloc;

  __shared__ __align__(16) _Float16 W1p[H1 * 128];      // 16 KB, shared by both b's
  __shared__ __align__(16) _Float16 MhT2[2][H0 * 64];   // 2 x 16 KB, per b; reused as combine scratch
  __shared__ __align__(16) float qS[2][DD];
  __shared__ __align__(16) float cbS[2][H0];
  __shared__ __align__(16) float b1S[H1];
  __shared__ __align__(16) float WfS[H1];

  const float* qb = q + (size_t)b * DD;
  const float* kb = k + (size_t)b * TT * DD;
  const float* vb = v + (size_t)b * TT * DD;
  const int*   mb = mask + (size_t)b * TT;

  // ---- staging (before barrier 1) ----
  {
    const uint4* src = (const uint4*)(ws + WS_W1);
    uint4* dst = (uint4*)W1p;
    dst[tid]       = src[tid];
    dst[512 + tid] = src[512 + tid];
  }
  if (t256 < DD) qS[bloc][t256] = qb[t256];
  else if (t256 >= 64 && t256 < 64 + H0)
    cbS[bloc][t256 - 64] = ((const float*)(ws + WS_CB))[(size_t)b * H0 + (t256 - 64)];
  if (tid >= 192 && tid < 192 + H1) b1S[tid - 192] = b1[tid - 192];
  if (tid >= 448 && tid < 448 + H1) WfS[tid - 448] = Wf[tid - 448];
  __syncthreads();   // qS ready

  // M_b build: per b-group, thread = (h4 = (t256>>3)*4 rows, unit u = t256&7)
  {
    const _Float16* bcT = (const _Float16*)(ws + WS_BC);
    const _Float16* ddT = (const _Float16*)(ws + WS_DD);
    _Float16* Mh = MhT2[bloc];
    const int u    = t256 & 7;
    const int dblk = u * 8;
    const int h4 = (t256 >> 3) * 4;
    float q8[8];
    #pragma unroll
    for (int j = 0; j < 8; ++j) q8[j] = qS[bloc][dblk + j];
    #pragma unroll
    for (int hi = 0; hi < 4; ++hi) {
      const int h = h4 + hi;
      f16x8 bc8 = *(const f16x8*)(bcT + h * 64 + dblk);
      f16x8 dd8 = *(const f16x8*)(ddT + h * 64 + dblk);
      f16x8 o8;
      #pragma unroll
      for (int j = 0; j < 8; ++j)
        o8[j] = (_Float16)((float)bc8[j] + q8[j] * (float)dd8[j]);
      *(f16x8*)(&Mh[h * 64 + ((u ^ (h & 7)) << 3)]) = o8;
    }
  }
  __syncthreads();

  const int dof = 8 * g4;
  const int k8 = r16 & 7;   // MhT swizzle key
  const int kW = r16;       // W1p swizzle key
  const int tg = lane >> 4;
  const int dq = lane & 15;
  const _Float16* Mh = MhT2[bloc];

  // online-softmax + pooling state (o4 = lane's (tg, dq) partial)
  float m_run = -3e30f, s_run = 0.f;
  f32x4 o4 = {0.f, 0.f, 0.f, 0.f};

  // ---- fused pass: strips wid4, wid4+4, wid4+8, [wid4+12] ----
  #pragma unroll 1
  for (int s = wid4; s < 13; s += 4) {
    const int t0   = s * 16;
    const int trow = t0 + r16;
    int mm = (trow < TT) ? mb[trow] : -1;

    // k for this strip (inline load; occupancy hides latency)
    f16x8 bh0, bh1;
    {
      const float* kp = kb + (trow < TT ? trow : TT - 1) * DD;
      float4 kq0 = *(const float4*)(kp + dof);
      float4 kq1 = *(const float4*)(kp + dof + 4);
      float4 kq2 = *(const float4*)(kp + 32 + dof);
      float4 kq3 = *(const float4*)(kp + 32 + dof + 4);
      float f0[8] = {kq0.x, kq0.y, kq0.z, kq0.w, kq1.x, kq1.y, kq1.z, kq1.w};
      float f1[8] = {kq2.x, kq2.y, kq2.z, kq2.w, kq3.x, kq3.y, kq3.z, kq3.w};
      #pragma unroll
      for (int j = 0; j < 8; ++j) {
        bh0[j] = (_Float16)f0[j];
        bh1[j] = (_Float16)f1[j];
      }
    }
    // v for this strip's pooled t's (t = t0 + 4i + tg), issued early
    f32x4 vv0, vv1, vv2, vv3;
    {
      int ta = t0 + 0 + tg,  tb2 = t0 + 4 + tg;
      int tc = t0 + 8 + tg,  td = t0 + 12 + tg;
      vv0 = *(const f32x4*)(vb + (ta  < TT ? ta  : TT - 1) * DD + dq * 4);
      vv1 = *(const f32x4*)(vb + (tb2 < TT ? tb2 : TT - 1) * DD + dq * 4);
      vv2 = *(const f32x4*)(vb + (tc  < TT ? tc  : TT - 1) * DD + dq * 4);
      vv3 = *(const f32x4*)(vb + (td  < TT ? td  : TT - 1) * DD + dq * 4);
    }

    f32x4 acc1[4];
    #pragma unroll
    for (int c1 = 0; c1 < 4; ++c1) acc1[c1] = (f32x4){0.f, 0.f, 0.f, 0.f};

    #pragma unroll 1
    for (int m = 0; m < 4; ++m) {
      const _Float16* rowE = &Mh[((2 * m) * 16 + r16) * 64];
      const _Float16* rowO = rowE + 16 * 64;
      f16x8 afE0 = *(const f16x8*)(rowE + ((g4 ^ k8) << 3));
      f16x8 afE1 = *(const f16x8*)(rowE + (((g4 + 4) ^ k8) << 3));
      f32x4 a0e = {0.f, 0.f, 0.f, 0.f};
      a0e = __builtin_amdgcn_mfma_f32_16x16x32_f16(afE0, bh0, a0e, 0, 0, 0);
      a0e = __builtin_amdgcn_mfma_f32_16x16x32_f16(afE1, bh1, a0e, 0, 0, 0);
      f16x8 afO0 = *(const f16x8*)(rowO + ((g4 ^ k8) << 3));
      f16x8 afO1 = *(const f16x8*)(rowO + (((g4 + 4) ^ k8) << 3));
      f32x4 a0o = {0.f, 0.f, 0.f, 0.f};
      a0o = __builtin_amdgcn_mfma_f32_16x16x32_f16(afO0, bh0, a0o, 0, 0, 0);
      a0o = __builtin_amdgcn_mfma_f32_16x16x32_f16(afO1, bh1, a0o, 0, 0, 0);

      f32x4 cbe = *(const f32x4*)(&cbS[bloc][(2 * m) * 16 + 4 * g4]);
      f32x4 cbo = *(const f32x4*)(&cbS[bloc][(2 * m) * 16 + 16 + 4 * g4]);
      f16x8 hf;   // phi-layout: j<4 -> even block regs, j>=4 -> odd block regs
      #pragma unroll
      for (int r = 0; r < 4; ++r) {
        float he = a0e[r] + cbe[r];
        float ho = a0o[r] + cbo[r];
        hf[r]     = (_Float16)(he > 0.f ? he : 0.f);
        hf[4 + r] = (_Float16)(ho > 0.f ? ho : 0.f);
      }
      #pragma unroll
      for (int c1 = 0; c1 < 4; ++c1) {
        f16x8 af1 = *(const f16x8*)(&W1p[(c1 * 16 + r16) * 128
                                         + (((4 * m + g4) ^ kW) << 3)]);
        acc1[c1] = __builtin_amdgcn_mfma_f32_16x16x32_f16(af1, hf, acc1[c1], 0, 0, 0);
      }
    }

    float p = 0.f;
    #pragma unroll
    for (int c1 = 0; c1 < 4; ++c1) {
      f32x4 b14 = *(const f32x4*)(&b1S[c1 * 16 + 4 * g4]);
      f32x4 wf4 = *(const f32x4*)(&WfS[c1 * 16 + 4 * g4]);
      #pragma unroll
      for (int r = 0; r < 4; ++r) {
        float h1 = acc1[c1][r] + b14[r];
        h1 = h1 > 0.f ? h1 : 0.f;
        p = fmaf(h1, wf4[r], p);
      }
    }
    p += __shfl_xor(p, 16, 64);
    p += __shfl_xor(p, 32, 64);
    p = (mm == 1) ? p : (mm == 0 ? -1e30f : -2e30f);
    // p now valid on all lanes (logit for t0 + r16)

    // strip max (reduce over r16 bits; wave-uniform afterwards)
    float sm = p;
    sm = fmaxf(sm, __shfl_xor(sm, 1, 64));
    sm = fmaxf(sm, __shfl_xor(sm, 2, 64));
    sm = fmaxf(sm, __shfl_xor(sm, 4, 64));
    sm = fmaxf(sm, __shfl_xor(sm, 8, 64));
    float m_new = fmaxf(m_run, sm);
    float scale = __expf(m_run - m_new);
    s_run *= scale;
    #pragma unroll
    for (int j = 0; j < 4; ++j) o4[j] *= scale;
    {
      float w0 = __expf(__shfl(p,  0 + tg, 64) - m_new);
      float w1 = __expf(__shfl(p,  4 + tg, 64) - m_new);
      float w2 = __expf(__shfl(p,  8 + tg, 64) - m_new);
      float w3 = __expf(__shfl(p, 12 + tg, 64) - m_new);
      s_run += (w0 + w1) + (w2 + w3);
      #pragma unroll
      for (int j = 0; j < 4; ++j)
        o4[j] = fmaf(w0, vv0[j], fmaf(w1, vv1[j], fmaf(w2, vv2[j], fmaf(w3, vv3[j], o4[j]))));
    }
    m_run = m_new;
  }

  // in-wave reduce over tg (lane bits 4,5): o4 and s_run become tg-summed
  #pragma unroll
  for (int j = 0; j < 4; ++j) {
    o4[j] += __shfl_xor(o4[j], 16, 64);
    o4[j] += __shfl_xor(o4[j], 32, 64);
  }
  s_run += __shfl_xor(s_run, 16, 64);
  s_run += __shfl_xor(s_run, 32, 64);

  // ---- combine scratch aliases the dead MhT2 (all strip-loop reads done) ----
  __syncthreads();
  float* ob = (float*)&MhT2[bloc][0];   // per-b 16 KB region
  if (lane < 16) *(f32x4*)(&ob[wid4 * 64 + lane * 4]) = o4;
  if (lane == 0) { ob[256 + wid4] = m_run; ob[264 + wid4] = s_run; }
  __syncthreads();

  // ---- cross-wave flash combine (4 waves per b) ----
  if (t256 < DD) {
    float m0 = ob[256], m1 = ob[257], m2 = ob[258], m3 = ob[259];
    float mstar = fmaxf(fmaxf(m0, m1), fmaxf(m2, m3));
    float f0 = __expf(m0 - mstar), f1 = __expf(m1 - mstar);
    float f2 = __expf(m2 - mstar), f3 = __expf(m3 - mstar);
    float acc = ob[t256] * f0 + ob[64 + t256] * f1
              + ob[128 + t256] * f2 + ob[192 + t256] * f3;
    float stot = ob[264] * f0 + ob[265] * f1 + ob[266] * f2 + ob[267] * f3;
    out[(size_t)b * DD + t256] = acc / stot;
  }
}

extern "C" void kernel_launch(void* const* d_in, const int* in_sizes, int n_in,
                              void* d_out, int out_size, void* d_ws, size_t ws_size,
                              hipStream_t stream) {
  const float* q    = (const float*)d_in[0];
  const float* k    = (const float*)d_in[1];
  const float* v    = (const float*)d_in[2];
  const int*   mask = (const int*)d_in[3];
  const float* W0   = (const float*)d_in[4];
  const float* b0   = (const float*)d_in[5];
  const float* W1   = (const float*)d_in[6];
  const float* b1   = (const float*)d_in[7];
  const float* Wf   = (const float*)d_in[8];
  float* out = (float*)d_out;
  unsigned char* ws = (unsigned char*)d_ws;

  pre_fold<<<dim3(64), dim3(256), 0, stream>>>(W0, W1, ws);
  pre_cb<<<dim3(128), dim3(256), 0, stream>>>(q, W0, b0, ws);
  din_attn<<<dim3(NB / 2), dim3(BT), 0, stream>>>(q, k, v, mask, b1, Wf, ws, out);
}

// Round 27
// 113.390 us; speedup vs baseline: 1.0907x; 1.0907x over previous
//
#include <hip/hip_runtime.h>

typedef __attribute__((ext_vector_type(4))) _Float16 f16x4;
typedef __attribute__((ext_vector_type(8))) _Float16 f16x8;
typedef __attribute__((ext_vector_type(4))) float f32x4;

#define NB 4096
#define TT 200
#define DD 64
#define H0 128
#define H1 64
#define BT 512   // 8 waves: waves 0-3 -> b0, waves 4-7 -> b1

// ws layout (bytes)
#define WS_BC 0        // W0bcT fp16 [128][64] = 16384 B  (W0b - W0c, transposed)
#define WS_DD 16384    // W0dT  fp16 [128][64] = 16384 B  (W0d, transposed)
#define WS_W1 32768    // W1phi fp16 [64][128] = 16384 B  (phi-permuted, XOR-swizzled)
#define WS_CB 49152    // cb f32 [4096][128] = 2 MB

// ---- pre-kernel A: fold W0 -> fp16 transposed parts + phi-permuted W1 image ----
// phi(g4,jj) = 4*g4 + (jj&3) + 16*(jj>>2): the k-labeling that matches the
// layer0 D-fragment layout, so layer1's A-frag is ONE b128 per (c1,m).
// W1 image XOR-swizzled on 16B units: unit ^= (row & 15) -> conflict-free b128.
__global__ __launch_bounds__(256)
void pre_fold(const float* __restrict__ W0, const float* __restrict__ W1,
              unsigned char* __restrict__ ws)
{
  int idx = blockIdx.x * 256 + threadIdx.x;   // grid 64 -> 16384 threads
  _Float16* bcT  = (_Float16*)(ws + WS_BC);
  _Float16* ddT  = (_Float16*)(ws + WS_DD);
  _Float16* w1p  = (_Float16*)(ws + WS_W1);
  if (idx < 8192) {
    int h = idx >> 6, d = idx & 63;
    bcT[h * 64 + d] = (_Float16)(W0[(64 + d) * H0 + h] - W0[(128 + d) * H0 + h]);
    ddT[h * 64 + d] = (_Float16)(W0[(192 + d) * H0 + h]);
  } else {
    int i = idx - 8192;                       // 0..8191
    int jrow = i >> 7, p = i & 127;           // p = m*32 + g4p*8 + jj
    int m = p >> 5, g4p = (p >> 3) & 3, jj = p & 7;
    int h = 32 * m + 16 * (jj >> 2) + 4 * g4p + (jj & 3);
    int up = p >> 3, wi = p & 7;              // 16B unit, half-within-unit
    w1p[jrow * 128 + (((up ^ (jrow & 15)) << 3) | wi)] = (_Float16)W1[h * H1 + jrow];
  }
}

// ---- pre-kernel B: cb[b][h] = b0[h] + q[b] @ (W0a + W0c) ----
__global__ __launch_bounds__(256)
void pre_cb(const float* __restrict__ q, const float* __restrict__ W0,
            const float* __restrict__ b0, unsigned char* __restrict__ ws)
{
  __shared__ float WacS[DD * H0];   // 32 KB, [d][h]
  __shared__ float qS2[2][DD];
  const int tid = threadIdx.x;
  float* cb = (float*)(ws + WS_CB);

  #pragma unroll 4
  for (int i = 0; i < 32; ++i) {
    int idx = i * 256 + tid;
    int d = idx >> 7, h = idx & 127;
    WacS[idx] = W0[d * H0 + h] + W0[(128 + d) * H0 + h];
  }
  __syncthreads();

  const int half = tid >> 7, h = tid & 127;
  #pragma unroll 1
  for (int p = 0; p < 16; ++p) {
    int bpair = blockIdx.x * 32 + p * 2;      // grid 128
    if (tid < DD) qS2[0][tid] = q[(size_t)bpair * DD + tid];
    else if (tid >= 128 && tid < 128 + DD) qS2[1][tid - 128] = q[(size_t)(bpair + 1) * DD + (tid - 128)];
    __syncthreads();
    float s = b0[h];
    #pragma unroll 8
    for (int d = 0; d < DD; ++d) s = fmaf(qS2[half][d], WacS[d * H0 + h], s);
    cb[(size_t)(bpair + half) * H0 + h] = s;
    __syncthreads();
  }
}

// ---- main kernel ----
// Transposed-GEMM DIN attention, fp16 weights/acts, fp32 accum/softmax, both
// layers on mfma_f32_16x16x32_f16 (k-relabeling: layer1 uses phi = D-frag
// layout; exact since k is contracted and A/B lane->k maps are identical).
// R27 = the TRUE R21 (114 us verified): fused online softmax+pooling; two b's
// per 512-thread block; (512,4); SEPARATE owav/msv/ssv combine arrays
// (LDS 53760). R26's "restore" kept the MhT2-aliased combine (LDS 51200) and
// measured 123.7 us with 9 MB spill-writes -- the type-punned alias, not
// setprio, was R25/R26's regression. Full design-space map (R0-R26):
// occupancy capped at the unique clean register point (512,4); tighter/looser
// bounds spill or balloon; ILP, prologue-amortization, persistence, prefetch,
// early-v, setprio, combine-alias all neutral-or-regress.
__global__ __launch_bounds__(BT, 4)
void din_attn(const float* __restrict__ q, const float* __restrict__ k,
              const float* __restrict__ v, const int* __restrict__ mask,
              const float* __restrict__ b1, const float* __restrict__ Wf,
              const unsigned char* __restrict__ ws, float* __restrict__ out)
{
  const int tid  = threadIdx.x;    // 0..511
  const int bloc = tid >> 8;       // 0/1: which b of the pair
  const int t256 = tid & 255;      // thread id within the b-group
  const int lane = tid & 63;
  const int wid4 = (tid >> 6) & 3; // wave within the b-group
  const int r16  = lane & 15;
  const int g4   = lane >> 4;
  const int b    = blockIdx.x * 2 + bloc;

  __shared__ __align__(16) _Float16 W1p[H1 * 128];      // 16 KB, shared by both b's
  __shared__ __align__(16) _Float16 MhT2[2][H0 * 64];   // 2 x 16 KB, per b
  __shared__ __align__(16) float qS[2][DD];
  __shared__ __align__(16) float cbS[2][H0];
  __shared__ __align__(16) float b1S[H1];
  __shared__ __align__(16) float WfS[H1];
  __shared__ __align__(16) float owav[2][4][DD];        // per-wave pooled o
  __shared__ float msv[2][4];
  __shared__ float ssv[2][4];

  const float* qb = q + (size_t)b * DD;
  const float* kb = k + (size_t)b * TT * DD;
  const float* vb = v + (size_t)b * TT * DD;
  const int*   mb = mask + (size_t)b * TT;

  // ---- staging (before barrier 1) ----
  {
    const uint4* src = (const uint4*)(ws + WS_W1);
    uint4* dst = (uint4*)W1p;
    dst[tid]       = src[tid];
    dst[512 + tid] = src[512 + tid];
  }
  if (t256 < DD) qS[bloc][t256] = qb[t256];
  else if (t256 >= 64 && t256 < 64 + H0)
    cbS[bloc][t256 - 64] = ((const float*)(ws + WS_CB))[(size_t)b * H0 + (t256 - 64)];
  if (tid >= 192 && tid < 192 + H1) b1S[tid - 192] = b1[tid - 192];
  if (tid >= 448 && tid < 448 + H1) WfS[tid - 448] = Wf[tid - 448];
  __syncthreads();   // qS ready

  // M_b build: per b-group, thread = (h4 = (t256>>3)*4 rows, unit u = t256&7)
  {
    const _Float16* bcT = (const _Float16*)(ws + WS_BC);
    const _Float16* ddT = (const _Float16*)(ws + WS_DD);
    _Float16* Mh = MhT2[bloc];
    const int u    = t256 & 7;
    const int dblk = u * 8;
    const int h4 = (t256 >> 3) * 4;
    float q8[8];
    #pragma unroll
    for (int j = 0; j < 8; ++j) q8[j] = qS[bloc][dblk + j];
    #pragma unroll
    for (int hi = 0; hi < 4; ++hi) {
      const int h = h4 + hi;
      f16x8 bc8 = *(const f16x8*)(bcT + h * 64 + dblk);
      f16x8 dd8 = *(const f16x8*)(ddT + h * 64 + dblk);
      f16x8 o8;
      #pragma unroll
      for (int j = 0; j < 8; ++j)
        o8[j] = (_Float16)((float)bc8[j] + q8[j] * (float)dd8[j]);
      *(f16x8*)(&Mh[h * 64 + ((u ^ (h & 7)) << 3)]) = o8;
    }
  }
  __syncthreads();

  const int dof = 8 * g4;
  const int k8 = r16 & 7;   // MhT swizzle key
  const int kW = r16;       // W1p swizzle key
  const int tg = lane >> 4;
  const int dq = lane & 15;
  const _Float16* Mh = MhT2[bloc];

  // online-softmax + pooling state (o4 = lane's (tg, dq) partial)
  float m_run = -3e30f, s_run = 0.f;
  f32x4 o4 = {0.f, 0.f, 0.f, 0.f};

  // ---- fused pass: strips wid4, wid4+4, wid4+8, [wid4+12] ----
  #pragma unroll 1
  for (int s = wid4; s < 13; s += 4) {
    const int t0   = s * 16;
    const int trow = t0 + r16;
    int mm = (trow < TT) ? mb[trow] : -1;

    // k for this strip (inline load; occupancy hides latency)
    f16x8 bh0, bh1;
    {
      const float* kp = kb + (trow < TT ? trow : TT - 1) * DD;
      float4 kq0 = *(const float4*)(kp + dof);
      float4 kq1 = *(const float4*)(kp + dof + 4);
      float4 kq2 = *(const float4*)(kp + 32 + dof);
      float4 kq3 = *(const float4*)(kp + 32 + dof + 4);
      float f0[8] = {kq0.x, kq0.y, kq0.z, kq0.w, kq1.x, kq1.y, kq1.z, kq1.w};
      float f1[8] = {kq2.x, kq2.y, kq2.z, kq2.w, kq3.x, kq3.y, kq3.z, kq3.w};
      #pragma unroll
      for (int j = 0; j < 8; ++j) {
        bh0[j] = (_Float16)f0[j];
        bh1[j] = (_Float16)f1[j];
      }
    }
    // v for this strip's pooled t's (t = t0 + 4i + tg), issued early
    f32x4 vv0, vv1, vv2, vv3;
    {
      int ta = t0 + 0 + tg,  tb2 = t0 + 4 + tg;
      int tc = t0 + 8 + tg,  td = t0 + 12 + tg;
      vv0 = *(const f32x4*)(vb + (ta  < TT ? ta  : TT - 1) * DD + dq * 4);
      vv1 = *(const f32x4*)(vb + (tb2 < TT ? tb2 : TT - 1) * DD + dq * 4);
      vv2 = *(const f32x4*)(vb + (tc  < TT ? tc  : TT - 1) * DD + dq * 4);
      vv3 = *(const f32x4*)(vb + (td  < TT ? td  : TT - 1) * DD + dq * 4);
    }

    f32x4 acc1[4];
    #pragma unroll
    for (int c1 = 0; c1 < 4; ++c1) acc1[c1] = (f32x4){0.f, 0.f, 0.f, 0.f};

    #pragma unroll 1
    for (int m = 0; m < 4; ++m) {
      const _Float16* rowE = &Mh[((2 * m) * 16 + r16) * 64];
      const _Float16* rowO = rowE + 16 * 64;
      f16x8 afE0 = *(const f16x8*)(rowE + ((g4 ^ k8) << 3));
      f16x8 afE1 = *(const f16x8*)(rowE + (((g4 + 4) ^ k8) << 3));
      f32x4 a0e = {0.f, 0.f, 0.f, 0.f};
      a0e = __builtin_amdgcn_mfma_f32_16x16x32_f16(afE0, bh0, a0e, 0, 0, 0);
      a0e = __builtin_amdgcn_mfma_f32_16x16x32_f16(afE1, bh1, a0e, 0, 0, 0);
      f16x8 afO0 = *(const f16x8*)(rowO + ((g4 ^ k8) << 3));
      f16x8 afO1 = *(const f16x8*)(rowO + (((g4 + 4) ^ k8) << 3));
      f32x4 a0o = {0.f, 0.f, 0.f, 0.f};
      a0o = __builtin_amdgcn_mfma_f32_16x16x32_f16(afO0, bh0, a0o, 0, 0, 0);
      a0o = __builtin_amdgcn_mfma_f32_16x16x32_f16(afO1, bh1, a0o, 0, 0, 0);

      f32x4 cbe = *(const f32x4*)(&cbS[bloc][(2 * m) * 16 + 4 * g4]);
      f32x4 cbo = *(const f32x4*)(&cbS[bloc][(2 * m) * 16 + 16 + 4 * g4]);
      f16x8 hf;   // phi-layout: j<4 -> even block regs, j>=4 -> odd block regs
      #pragma unroll
      for (int r = 0; r < 4; ++r) {
        float he = a0e[r] + cbe[r];
        float ho = a0o[r] + cbo[r];
        hf[r]     = (_Float16)(he > 0.f ? he : 0.f);
        hf[4 + r] = (_Float16)(ho > 0.f ? ho : 0.f);
      }
      #pragma unroll
      for (int c1 = 0; c1 < 4; ++c1) {
        f16x8 af1 = *(const f16x8*)(&W1p[(c1 * 16 + r16) * 128
                                         + (((4 * m + g4) ^ kW) << 3)]);
        acc1[c1] = __builtin_amdgcn_mfma_f32_16x16x32_f16(af1, hf, acc1[c1], 0, 0, 0);
      }
    }

    float p = 0.f;
    #pragma unroll
    for (int c1 = 0; c1 < 4; ++c1) {
      f32x4 b14 = *(const f32x4*)(&b1S[c1 * 16 + 4 * g4]);
      f32x4 wf4 = *(const f32x4*)(&WfS[c1 * 16 + 4 * g4]);
      #pragma unroll
      for (int r = 0; r < 4; ++r) {
        float h1 = acc1[c1][r] + b14[r];
        h1 = h1 > 0.f ? h1 : 0.f;
        p = fmaf(h1, wf4[r], p);
      }
    }
    p += __shfl_xor(p, 16, 64);
    p += __shfl_xor(p, 32, 64);
    p = (mm == 1) ? p : (mm == 0 ? -1e30f : -2e30f);
    // p now valid on all lanes (logit for t0 + r16)

    // strip max (reduce over r16 bits; wave-uniform afterwards)
    float sm = p;
    sm = fmaxf(sm, __shfl_xor(sm, 1, 64));
    sm = fmaxf(sm, __shfl_xor(sm, 2, 64));
    sm = fmaxf(sm, __shfl_xor(sm, 4, 64));
    sm = fmaxf(sm, __shfl_xor(sm, 8, 64));
    float m_new = fmaxf(m_run, sm);
    float scale = __expf(m_run - m_new);
    s_run *= scale;
    #pragma unroll
    for (int j = 0; j < 4; ++j) o4[j] *= scale;
    {
      float w0 = __expf(__shfl(p,  0 + tg, 64) - m_new);
      float w1 = __expf(__shfl(p,  4 + tg, 64) - m_new);
      float w2 = __expf(__shfl(p,  8 + tg, 64) - m_new);
      float w3 = __expf(__shfl(p, 12 + tg, 64) - m_new);
      s_run += (w0 + w1) + (w2 + w3);
      #pragma unroll
      for (int j = 0; j < 4; ++j)
        o4[j] = fmaf(w0, vv0[j], fmaf(w1, vv1[j], fmaf(w2, vv2[j], fmaf(w3, vv3[j], o4[j]))));
    }
    m_run = m_new;
  }

  // in-wave reduce over tg (lane bits 4,5): o4 and s_run become tg-summed
  #pragma unroll
  for (int j = 0; j < 4; ++j) {
    o4[j] += __shfl_xor(o4[j], 16, 64);
    o4[j] += __shfl_xor(o4[j], 32, 64);
  }
  s_run += __shfl_xor(s_run, 16, 64);
  s_run += __shfl_xor(s_run, 32, 64);
  if (lane < 16) {
    *(f32x4*)(&owav[bloc][wid4][lane * 4]) = o4;
    if (lane == 0) { msv[bloc][wid4] = m_run; ssv[bloc][wid4] = s_run; }
  }
  __syncthreads();

  // ---- cross-wave flash combine (4 waves per b) ----
  if (t256 < DD) {
    float m0 = msv[bloc][0], m1 = msv[bloc][1];
    float m2 = msv[bloc][2], m3 = msv[bloc][3];
    float mstar = fmaxf(fmaxf(m0, m1), fmaxf(m2, m3));
    float f0 = __expf(m0 - mstar), f1 = __expf(m1 - mstar);
    float f2 = __expf(m2 - mstar), f3 = __expf(m3 - mstar);
    float acc = owav[bloc][0][t256] * f0 + owav[bloc][1][t256] * f1
              + owav[bloc][2][t256] * f2 + owav[bloc][3][t256] * f3;
    float stot = ssv[bloc][0] * f0 + ssv[bloc][1] * f1
               + ssv[bloc][2] * f2 + ssv[bloc][3] * f3;
    out[(size_t)b * DD + t256] = acc / stot;
  }
}

extern "C" void kernel_launch(void* const* d_in, const int* in_sizes, int n_in,
                              void* d_out, int out_size, void* d_ws, size_t ws_size,
                              hipStream_t stream) {
  const float* q    = (const float*)d_in[0];
  const float* k    = (const float*)d_in[1];
  const float* v    = (const float*)d_in[2];
  const int*   mask = (const int*)d_in[3];
  const float* W0   = (const float*)d_in[4];
  const float* b0   = (const float*)d_in[5];
  const float* W1   = (const float*)d_in[6];
  const float* b1   = (const float*)d_in[7];
  const float* Wf   = (const float*)d_in[8];
  float* out = (float*)d_out;
  unsigned char* ws = (unsigned char*)d_ws;

  pre_fold<<<dim3(64), dim3(256), 0, stream>>>(W0, W1, ws);
  pre_cb<<<dim3(128), dim3(256), 0, stream>>>(q, W0, b0, ws);
  din_attn<<<dim3(NB / 2), dim3(BT), 0, stream>>>(q, k, v, mask, b1, Wf, ws, out);
}